// Round 4
// baseline (328.992 us; speedup 1.0000x reference)
//
#include <hip/hip_runtime.h>
#include <hip/hip_bf16.h>
#include <hip/hip_cooperative_groups.h>

namespace cg = cooperative_groups;

#define MASK_ID 50264
#define Bn 16
#define Sn 2048
#define Hn 1024
#define Ln 128

typedef __attribute__((ext_vector_type(8))) short short8;
typedef __attribute__((ext_vector_type(4))) float f32x4;

__device__ __forceinline__ unsigned short f2bf(float f) {
    __hip_bfloat16 h = __float2bfloat16(f);
    return __builtin_bit_cast(unsigned short, h);
}
__device__ __forceinline__ void gload16(const void* g, void* l) {
    __builtin_amdgcn_global_load_lds((const __attribute__((address_space(1))) void*)g,
                                     (__attribute__((address_space(3))) void*)l, 16, 0, 0);
}

// One cooperative kernel, grid 512 x 256 (2 blocks/CU), three phases split by grid.sync().
__global__ __launch_bounds__(256, 2) void fused_k(
        const int* __restrict__ ids, const float* __restrict__ q,
        const float* __restrict__ seq, const int* __restrict__ offsets,
        const float* __restrict__ W, const float* __restrict__ bias,
        const int* __restrict__ labels, const int* __restrict__ events,
        unsigned short* __restrict__ Apack, unsigned short* __restrict__ Wb,
        unsigned short* __restrict__ Qb,
        float* __restrict__ yn2p, float* __restrict__ dotp, float* __restrict__ xn2p,
        float* __restrict__ lossb, float* __restrict__ out)
{
    __shared__ unsigned short As[2][8192];   // 2 x 16KB : [128 rows][128B], chunk-XOR swizzled
    __shared__ unsigned short Bs[2][2048];   // 2 x 4KB  : [32 rows][128B], same swizzle
    __shared__ unsigned short qs[1024];      // 2KB, linear (broadcast reads)
    __shared__ float xvs[32];
    __shared__ float xred[2];
    __shared__ float red[128][2];
    __shared__ float csh[2][128][2];
    __shared__ float xnsh;
    __shared__ float nd[2][2];
    __shared__ int t4[4];

    cg::grid_group grid = cg::this_grid();
    const int blk = blockIdx.x;
    const int tid = threadIdx.x;
    const int wv = tid >> 6, l = tid & 63;

    // ================= phase A: gather + bf16 convert =================
    // 3072 rows (A:0..2047 gathered seq rows, W:2048..3071), 6 rows per block.
    #pragma unroll
    for (int i = 0; i < 6; ++i) {
        int row = blk * 6 + i;
        const float* src;
        unsigned short* dst;
        if (row < 2048) {
            int b = row >> 7, ll = row & 127;
            src = seq + ((size_t)b * Sn + (size_t)offsets[ll]) * Hn;
            dst = Apack + (size_t)row * Hn;
        } else {
            int r = row - 2048;
            src = W + (size_t)r * Hn;
            dst = Wb + (size_t)r * Hn;
        }
        float4 v = ((const float4*)src)[tid];
        ((ushort4*)dst)[tid] = make_ushort4(f2bf(v.x), f2bf(v.y), f2bf(v.z), f2bf(v.w));
    }
    if (blk < Bn) {   // maskpos + q-row convert for batch blk
        int b = blk;
        int lm = Sn;
        for (int s = tid; s < Sn; s += 256)
            if (ids[b * Sn + s] == MASK_ID) lm = min(lm, s);
        for (int m = 32; m; m >>= 1) lm = min(lm, __shfl_xor(lm, m));
        if (l == 0) t4[wv] = lm;
        __syncthreads();
        int mp = min(min(t4[0], t4[1]), min(t4[2], t4[3]));
        if (mp == Sn) mp = 0;
        const float* src = q + ((size_t)b * Sn + mp) * Hn;
        float4 v = ((const float4*)src)[tid];
        ((ushort4*)(Qb + b * Hn))[tid] = make_ushort4(f2bf(v.x), f2bf(v.y), f2bf(v.z), f2bf(v.w));
    }
    __threadfence();
    grid.sync();

    // ================= phase B: bf16 MFMA GEMM, 128x32 tile, BK=64 =================
    const int swz = (blk & 7) * 64 + (blk >> 3);   // bijective XCD swizzle (512 % 8 == 0)
    const int by = swz >> 5;                       // 0..15 (M tile = batch)
    const int bx = swz & 31;                       // 0..31 (N tile)
    const int rbase = by * 128, cbase = bx * 32;
    const int l15 = l & 15;
    const int kgrp = l >> 4;                       // 0..3
    const int swzB = (l & 7) << 4;                 // XOR byte pattern for fragment reads

    // staging: wave wv issue j covers rows (j*4+wv)*8 .. +8 ; lane -> row (l>>3), chunk (l&7)
    // LDS dest linear; global source chunk pre-swizzled: csrc = (l&7) ^ (l>>3)  (row&7 == l>>3)
    const int srow = l >> 3;
    const int srcC = ((l & 7) ^ srow) * 8;         // element offset
    const unsigned short* aS[4];
    #pragma unroll
    for (int j = 0; j < 4; ++j)
        aS[j] = Apack + (size_t)(rbase + (j * 4 + wv) * 8 + srow) * Hn + srcC;
    const unsigned short* bS = Wb + (size_t)(cbase + wv * 8 + srow) * Hn + srcC;
    char* AsB = (char*)As;
    char* BsB = (char*)Bs;
    char* qsB = (char*)qs;

    float bv0 = bias[cbase + l15];
    float bv1 = bias[cbase + 16 + l15];

    f32x4 acc00 = {0,0,0,0}, acc01 = {0,0,0,0}, acc10 = {0,0,0,0}, acc11 = {0,0,0,0};
    f32x4 xacc = {0,0,0,0};

    #define STAGE(buf, ks_) do { \
        int ko = (ks_) * 64; \
        _Pragma("unroll") \
        for (int j = 0; j < 4; ++j) \
            gload16(aS[j] + ko, AsB + (buf) * 16384 + (j * 4 + wv) * 1024); \
        gload16(bS + ko, BsB + (buf) * 4096 + wv * 1024); \
    } while (0)

    if (wv >= 2) gload16(Qb + by * Hn + ((wv - 2) * 64 + l) * 8, qsB + (wv - 2) * 1024);
    STAGE(0, 0);
    __syncthreads();
    for (int ks = 0; ks < 16; ++ks) {
        int cur = ks & 1;
        if (ks + 1 < 16) STAGE(cur ^ 1, ks + 1);
        const char* Ab = AsB + cur * 16384;
        const char* Bb = BsB + cur * 4096;
        #pragma unroll
        for (int ks2 = 0; ks2 < 2; ++ks2) {
            int co = (ks2 * 64 + kgrp * 16) ^ swzB;
            short8 af0 = *(const short8*)(Ab + (wv * 32 + l15) * 128 + co);
            short8 af1 = *(const short8*)(Ab + (wv * 32 + 16 + l15) * 128 + co);
            short8 bf0 = *(const short8*)(Bb + l15 * 128 + co);
            short8 bf1 = *(const short8*)(Bb + (16 + l15) * 128 + co);
            acc00 = __builtin_amdgcn_mfma_f32_16x16x32_bf16(af0, bf0, acc00, 0, 0, 0);
            acc01 = __builtin_amdgcn_mfma_f32_16x16x32_bf16(af0, bf1, acc01, 0, 0, 0);
            acc10 = __builtin_amdgcn_mfma_f32_16x16x32_bf16(af1, bf0, acc10, 0, 0, 0);
            acc11 = __builtin_amdgcn_mfma_f32_16x16x32_bf16(af1, bf1, acc11, 0, 0, 0);
            if (wv >= 2) {
                short8 aq = *(const short8*)(qsB + ks * 128 + ks2 * 64 + kgrp * 16);
                xacc = __builtin_amdgcn_mfma_f32_16x16x32_bf16(aq, (wv == 2) ? bf0 : bf1, xacc, 0, 0, 0);
            }
        }
        __syncthreads();
    }
    #undef STAGE

    // waves 2,3: publish x (all D rows identical; reg 0) and x^2 partial
    if (wv >= 2) {
        float xv = xacc[0] + ((wv == 2) ? bv0 : bv1);
        if (l < 16) xvs[(wv - 2) * 16 + l] = xv;
        float px = xv * xv;
        #pragma unroll
        for (int m = 1; m < 16; m <<= 1) px += __shfl_xor(px, m);
        if (l == 0) xred[wv - 2] = px;
    }
    __syncthreads();

    float xv0 = xvs[l15];
    float xv1 = xvs[16 + l15];
    #pragma unroll
    for (int mf = 0; mf < 2; ++mf) {
        f32x4 a0 = mf ? acc10 : acc00;
        f32x4 a1 = mf ? acc11 : acc01;
        #pragma unroll
        for (int reg = 0; reg < 4; ++reg) {
            float y0 = a0[reg] + bv0;
            float y1 = a1[reg] + bv1;
            float y2v = y0 * y0 + y1 * y1;
            float xyv = xv0 * y0 + xv1 * y1;
            #pragma unroll
            for (int m = 1; m < 16; m <<= 1) {
                y2v += __shfl_xor(y2v, m);
                xyv += __shfl_xor(xyv, m);
            }
            if ((l & 15) == 0) {
                int lrow = wv * 32 + mf * 16 + (l >> 4) * 4 + reg;
                red[lrow][0] = y2v;
                red[lrow][1] = xyv;
            }
        }
    }
    __syncthreads();
    if (tid < 128) yn2p[bx * 2048 + rbase + tid] = red[tid][0];
    else           dotp[bx * 2048 + rbase + tid - 128] = red[tid - 128][1];
    if (tid == 0)  xn2p[bx * 16 + by] = xred[0] + xred[1];

    __threadfence();
    grid.sync();

    // ================= phase C: per-batch loss (blocks 0..15) =================
    if (blk < Bn) {
        int b = blk;
        float xs = 0.f;
        if (tid < 32) xs = xn2p[tid * 16 + b];
        if (wv == 0) {
            #pragma unroll
            for (int m = 32; m; m >>= 1) xs += __shfl_xor(xs, m);
            if (tid == 0) xnsh = sqrtf(xs);
        }
        int rl = tid & 127, half = tid >> 7;
        int row = b * 128 + rl;
        float y2 = 0.f, dt = 0.f;
        #pragma unroll
        for (int i2 = 0; i2 < 16; ++i2) {
            int i = half * 16 + i2;
            y2 += yn2p[i * 2048 + row];
            dt += dotp[i * 2048 + row];
        }
        csh[half][rl][0] = y2;
        csh[half][rl][1] = dt;
        __syncthreads();
        float numt = 0.f, dent = 0.f;
        if (tid < 128) {
            float y2f = csh[0][tid][0] + csh[1][tid][0];
            float dtf = csh[0][tid][1] + csh[1][tid][1];
            float yn = sqrtf(y2f);
            float c = dtf / fmaxf(xnsh * yn, 1e-8f);
            float e = expf(c);
            int r2 = b * 128 + tid;
            numt = e * (float)labels[r2];
            dent = e * (float)events[r2];
        }
        #pragma unroll
        for (int m = 32; m; m >>= 1) { numt += __shfl_xor(numt, m); dent += __shfl_xor(dent, m); }
        if (l == 0 && wv < 2) { nd[wv][0] = numt; nd[wv][1] = dent; }
        __syncthreads();
        if (tid == 0) lossb[b] = logf(nd[0][1] + nd[1][1]) - logf(nd[0][0] + nd[1][0]);
    }
    __threadfence();
    grid.sync();

    // ================= phase D: mean =================
    if (blk == 0 && wv == 0) {
        float v = (l < Bn) ? lossb[l] : 0.f;
        #pragma unroll
        for (int m = 32; m; m >>= 1) v += __shfl_xor(v, m);
        if (l == 0) out[0] = v * (1.0f / Bn);
    }
}

extern "C" void kernel_launch(void* const* d_in, const int* in_sizes, int n_in,
                              void* d_out, int out_size, void* d_ws, size_t ws_size,
                              hipStream_t stream) {
    const int*   input_ids = (const int*)d_in[0];
    const float* q         = (const float*)d_in[1];
    const float* seq       = (const float*)d_in[2];
    const int*   events    = (const int*)d_in[3];
    const int*   labels    = (const int*)d_in[4];
    const int*   offsets   = (const int*)d_in[5];
    const float* W         = (const float*)d_in[7];
    const float* bias      = (const float*)d_in[8];
    float* out = (float*)d_out;

    char* ws = (char*)d_ws;
    unsigned short* Apack = (unsigned short*)(ws);                 // 4 MB
    unsigned short* Wb    = (unsigned short*)(ws + 4194304);       // 2 MB
    unsigned short* Qb    = (unsigned short*)(ws + 6291456);       // 32 KB
    float*          yn2p  = (float*)(ws + 6356992);                // 256 KB [32][2048]
    float*          dotp  = (float*)(ws + 6619136);                // 256 KB [32][2048]
    float*          xn2p  = (float*)(ws + 6881280);                // 2 KB   [32][16]
    float*          lossb = (float*)(ws + 6883328);                // 64 B

    void* args[] = {(void*)&input_ids, (void*)&q, (void*)&seq, (void*)&offsets,
                    (void*)&W, (void*)&bias, (void*)&labels, (void*)&events,
                    (void*)&Apack, (void*)&Wb, (void*)&Qb,
                    (void*)&yn2p, (void*)&dotp, (void*)&xn2p,
                    (void*)&lossb, (void*)&out};
    hipLaunchCooperativeKernel((const void*)fused_k, dim3(512), dim3(256), args, 0, stream);
}

// Round 5
// 95.216 us; speedup vs baseline: 3.4552x; 3.4552x over previous
//
#include <hip/hip_runtime.h>
#include <hip/hip_bf16.h>

#define MASK_ID 50264
#define Bn 16
#define Sn 2048
#define Hn 1024
#define Ln 128

typedef __attribute__((ext_vector_type(8))) short short8;
typedef __attribute__((ext_vector_type(4))) float f32x4;

__device__ __forceinline__ unsigned short f2bf(float f) {
    __hip_bfloat16 h = __float2bfloat16(f);
    return __builtin_bit_cast(unsigned short, h);
}
__device__ __forceinline__ void st_agent(float* p, float v) {
    __hip_atomic_store(p, v, __ATOMIC_RELAXED, __HIP_MEMORY_SCOPE_AGENT);
}
__device__ __forceinline__ float ld_agent(const float* p) {
    return __hip_atomic_load(p, __ATOMIC_RELAXED, __HIP_MEMORY_SCOPE_AGENT);
}

// ONE kernel: 512 blocks (16 M-tiles x 32 N-tiles), 256 threads (4 waves).
// Per block: maskpos + q-row bf16 -> LDS; K-loop reg-stages f32 seq/W -> bf16
// swizzled LDS -> MFMA; epilogue writes per-tile partials; last block finalizes.
__global__ __launch_bounds__(256, 2) void fused1_k(
        const int* __restrict__ ids, const float* __restrict__ q,
        const float* __restrict__ seq, const int* __restrict__ offsets,
        const float* __restrict__ W, const float* __restrict__ bias,
        const int* __restrict__ labels, const int* __restrict__ events,
        float* __restrict__ yn2p, float* __restrict__ dotp, float* __restrict__ xn2p,
        unsigned int* __restrict__ done, float* __restrict__ out)
{
    __shared__ unsigned short As[2][8192];   // 2 x 16KB : [128 rows][128B] XOR-swizzled
    __shared__ unsigned short Bs[2][2048];   // 2 x 4KB  : [32 rows][128B] same swizzle
    __shared__ unsigned short qs[1024];      // 2KB linear
    __shared__ int   offs[128];
    __shared__ int   t4[4];
    __shared__ float xvs[32], xred[2];
    __shared__ float red[128][2];
    __shared__ int   lastf;
    __shared__ float xns[16], numL[16], denL[16], ln16[16];

    const int blk = blockIdx.x, tid = threadIdx.x;
    const int wv = tid >> 6, l = tid & 63;
    // XCD partition: XCD x gets 4 by x 16 bx (~4MB working set, L2-resident)
    const int x = blk & 7, ib = blk >> 3;
    const int by = (x >> 1) * 4 + (ib >> 4);
    const int bx = (x & 1) * 16 + (ib & 15);
    const int rbase = by * 128, cbase = bx * 32;
    const int l15 = l & 15, kgrp = l >> 4;

    if (tid < 128) offs[tid] = offsets[tid];

    // ---- maskpos for this block's batch ----
    int lm = Sn;
    const int* idrow = ids + by * Sn;
    for (int s = tid; s < Sn; s += 256)
        if (idrow[s] == MASK_ID) lm = min(lm, s);
    #pragma unroll
    for (int m = 32; m; m >>= 1) lm = min(lm, __shfl_xor(lm, m));
    if (l == 0) t4[wv] = lm;
    __syncthreads();
    int mp = min(min(t4[0], t4[1]), min(t4[2], t4[3]));
    if (mp == Sn) mp = 0;

    // ---- q row -> bf16 LDS ----
    {
        float4 v = ((const float4*)(q + ((size_t)by * Sn + mp) * Hn))[tid];
        ((ushort4*)qs)[tid] = make_ushort4(f2bf(v.x), f2bf(v.y), f2bf(v.z), f2bf(v.w));
    }

    // ---- staging geometry: 16 lanes cover one row's 256B (f32) per issue ----
    const int srow = tid >> 4;          // 0..15
    const int schunk = tid & 15;        // 16B f32 chunk
    const float* aP[8];
    #pragma unroll
    for (int j = 0; j < 8; ++j)
        aP[j] = seq + ((size_t)by * Sn + (size_t)offs[j * 16 + srow]) * Hn + schunk * 4;
    const float* bP[2];
    #pragma unroll
    for (int j = 0; j < 2; ++j)
        bP[j] = W + (size_t)(cbase + j * 16 + srow) * Hn + schunk * 4;
    // bf16 LDS write offset (row = j*16+srow, granule g = schunk>>1, half = schunk&1)
    const int wbyte = srow * 128 + (((schunk >> 1) ^ (srow & 7)) * 16 + (schunk & 1) * 8);
    char* AsB = (char*)As;
    char* BsB = (char*)Bs;
    char* qsB = (char*)qs;

    // fragment read geometry (identical to verified round-4)
    const int swzB = (l & 7) << 4;
    const int aro = (wv * 32 + l15) * 128;

    float bv0 = bias[cbase + l15];
    float bv1 = bias[cbase + 16 + l15];

    f32x4 acc00 = {0,0,0,0}, acc01 = {0,0,0,0}, acc10 = {0,0,0,0}, acc11 = {0,0,0,0};
    f32x4 xacc = {0,0,0,0};

    float4 La[8], Lb[2];
    #define LOADS(ks_) do { \
        _Pragma("unroll") \
        for (int j = 0; j < 8; ++j) La[j] = *(const float4*)(aP[j] + (ks_) * 64); \
        Lb[0] = *(const float4*)(bP[0] + (ks_) * 64); \
        Lb[1] = *(const float4*)(bP[1] + (ks_) * 64); \
    } while (0)
    #define WRITES(buf) do { \
        _Pragma("unroll") \
        for (int j = 0; j < 8; ++j) \
            *(ushort4*)(AsB + (buf) * 16384 + wbyte + j * 2048) = \
                make_ushort4(f2bf(La[j].x), f2bf(La[j].y), f2bf(La[j].z), f2bf(La[j].w)); \
        _Pragma("unroll") \
        for (int j = 0; j < 2; ++j) \
            *(ushort4*)(BsB + (buf) * 4096 + wbyte + j * 2048) = \
                make_ushort4(f2bf(Lb[j].x), f2bf(Lb[j].y), f2bf(Lb[j].z), f2bf(Lb[j].w)); \
    } while (0)

    LOADS(0); WRITES(0);
    __syncthreads();
    for (int ks = 0; ks < 16; ++ks) {
        int cur = ks & 1;
        if (ks < 15) LOADS(ks + 1);        // issue early (hides under MFMA)
        const char* Ab = AsB + cur * 16384;
        const char* Bb = BsB + cur * 4096;
        #pragma unroll
        for (int ks2 = 0; ks2 < 2; ++ks2) {
            int co = (ks2 * 64 + kgrp * 16) ^ swzB;
            short8 af0 = *(const short8*)(Ab + aro + co);
            short8 af1 = *(const short8*)(Ab + aro + 16 * 128 + co);
            short8 bf0 = *(const short8*)(Bb + l15 * 128 + co);
            short8 bf1 = *(const short8*)(Bb + (16 + l15) * 128 + co);
            acc00 = __builtin_amdgcn_mfma_f32_16x16x32_bf16(af0, bf0, acc00, 0, 0, 0);
            acc01 = __builtin_amdgcn_mfma_f32_16x16x32_bf16(af0, bf1, acc01, 0, 0, 0);
            acc10 = __builtin_amdgcn_mfma_f32_16x16x32_bf16(af1, bf0, acc10, 0, 0, 0);
            acc11 = __builtin_amdgcn_mfma_f32_16x16x32_bf16(af1, bf1, acc11, 0, 0, 0);
            if (wv >= 2) {
                short8 aq = *(const short8*)(qsB + ks * 128 + ks2 * 64 + kgrp * 16);
                xacc = __builtin_amdgcn_mfma_f32_16x16x32_bf16(aq, (wv == 2) ? bf0 : bf1, xacc, 0, 0, 0);
            }
        }
        if (ks < 15) WRITES(cur ^ 1);      // write late (after vmcnt lands)
        __syncthreads();
    }
    #undef LOADS
    #undef WRITES

    // ---- x publish (waves 2,3) ----
    if (wv >= 2) {
        float xv = xacc[0] + ((wv == 2) ? bv0 : bv1);
        if (l < 16) xvs[(wv - 2) * 16 + l] = xv;
        float px = xv * xv;
        #pragma unroll
        for (int m = 1; m < 16; m <<= 1) px += __shfl_xor(px, m);
        if (l == 0) xred[wv - 2] = px;
    }
    __syncthreads();

    // ---- per-row partial ||y||^2, x.y over this block's 32 cols ----
    float xv0 = xvs[l15];
    float xv1 = xvs[16 + l15];
    #pragma unroll
    for (int mf = 0; mf < 2; ++mf) {
        f32x4 a0 = mf ? acc10 : acc00;
        f32x4 a1 = mf ? acc11 : acc01;
        #pragma unroll
        for (int reg = 0; reg < 4; ++reg) {
            float y0 = a0[reg] + bv0;
            float y1 = a1[reg] + bv1;
            float y2v = y0 * y0 + y1 * y1;
            float xyv = xv0 * y0 + xv1 * y1;
            #pragma unroll
            for (int m = 1; m < 16; m <<= 1) {
                y2v += __shfl_xor(y2v, m);
                xyv += __shfl_xor(xyv, m);
            }
            if ((l & 15) == 0) {
                int lrow = wv * 32 + mf * 16 + (l >> 4) * 4 + reg;
                red[lrow][0] = y2v;
                red[lrow][1] = xyv;
            }
        }
    }
    __syncthreads();
    if (tid < 128) st_agent(&yn2p[bx * 2048 + rbase + tid], red[tid][0]);
    else           st_agent(&dotp[bx * 2048 + rbase + tid - 128], red[tid - 128][1]);
    if (tid == 0)  st_agent(&xn2p[bx * 16 + by], xred[0] + xred[1]);

    // ---- last-block-done: no grid barrier, no spin ----
    __threadfence();
    if (tid == 0) {
        unsigned int old = atomicAdd(done, 1u);
        lastf = (old == 511) ? 1 : 0;
    }
    __syncthreads();
    if (!lastf) return;
    __threadfence();

    // ---- finalize (one block) ----
    if (tid < 16) {
        float s = 0.f;
        #pragma unroll
        for (int b2 = 0; b2 < 32; ++b2) s += ld_agent(&xn2p[b2 * 16 + tid]);
        xns[tid] = sqrtf(s);
        numL[tid] = 0.f;
        denL[tid] = 0.f;
    }
    __syncthreads();
    #pragma unroll
    for (int r8 = 0; r8 < 8; ++r8) {
        int row = r8 * 256 + tid;
        float y2 = 0.f, dt = 0.f;
        #pragma unroll
        for (int b2 = 0; b2 < 32; ++b2) {
            y2 += ld_agent(&yn2p[b2 * 2048 + row]);
            dt += ld_agent(&dotp[b2 * 2048 + row]);
        }
        int b = row >> 7;                       // uniform per wave (64 rows, same batch)
        float c = dt / fmaxf(xns[b] * sqrtf(y2), 1e-8f);
        float e = expf(c);
        float numt = e * (float)labels[row];
        float dent = e * (float)events[row];
        #pragma unroll
        for (int m = 32; m; m >>= 1) { numt += __shfl_xor(numt, m); dent += __shfl_xor(dent, m); }
        if (l == 0) { atomicAdd(&numL[b], numt); atomicAdd(&denL[b], dent); }  // 2 adds/batch, commutative
    }
    __syncthreads();
    if (tid < 16) ln16[tid] = logf(denL[tid]) - logf(numL[tid]);
    __syncthreads();
    if (wv == 0) {
        float v = (l < 16) ? ln16[l] : 0.f;
        #pragma unroll
        for (int m = 32; m; m >>= 1) v += __shfl_xor(v, m);
        if (l == 0) out[0] = v * (1.0f / Bn);
    }
}

extern "C" void kernel_launch(void* const* d_in, const int* in_sizes, int n_in,
                              void* d_out, int out_size, void* d_ws, size_t ws_size,
                              hipStream_t stream) {
    const int*   input_ids = (const int*)d_in[0];
    const float* q         = (const float*)d_in[1];
    const float* seq       = (const float*)d_in[2];
    const int*   events    = (const int*)d_in[3];
    const int*   labels    = (const int*)d_in[4];
    const int*   offsets   = (const int*)d_in[5];
    const float* W         = (const float*)d_in[7];
    const float* bias      = (const float*)d_in[8];
    float* out = (float*)d_out;

    char* ws = (char*)d_ws;
    float*        yn2p = (float*)(ws);              // 256 KB [32][2048]
    float*        dotp = (float*)(ws + 262144);     // 256 KB [32][2048]
    float*        xn2p = (float*)(ws + 524288);     //   2 KB [32][16]
    unsigned int* done = (unsigned int*)(ws + 526336);

    hipMemsetAsync(done, 0, 64, stream);
    fused1_k<<<512, 256, 0, stream>>>(input_ids, q, seq, offsets, W, bias,
                                      labels, events, yn2p, dotp, xn2p, done, out);
}